// Round 5
// baseline (2303.570 us; speedup 1.0000x reference)
//
#include <hip/hip_runtime.h>
#include <hip/hip_bf16.h>

#define NH 4
#define DH 256
#define DMODEL 1024
#define BB 4
#define SS 2048

typedef __attribute__((ext_vector_type(4))) float f32x4;
typedef __attribute__((ext_vector_type(8))) short bf16x8;
typedef __attribute__((ext_vector_type(4))) int i32x4;

__device__ __forceinline__ int dot4i8(int acc, int a, int b) {
#if __has_builtin(__builtin_amdgcn_sdot4)
    return __builtin_amdgcn_sdot4(a, b, acc, false);
#else
#pragma unroll
    for (int i = 0; i < 4; ++i) {
        int av = (a << (24 - 8 * i)) >> 24;
        int bv = (b << (24 - 8 * i)) >> 24;
        acc += av * bv;
    }
    return acc;
#endif
}

// Raw workgroup barrier: orders LDS only; global loads/stores stay in flight.
__device__ __forceinline__ void wg_barrier() {
    asm volatile("s_waitcnt lgkmcnt(0)" ::: "memory");
    __builtin_amdgcn_s_barrier();
    __builtin_amdgcn_sched_barrier(0);
}

// ---------------- conv + swish ----------------
__global__ void k_conv(const float* __restrict__ x, const float* __restrict__ cw,
                       const float* __restrict__ cb, float* __restrict__ xc) {
    int bs = blockIdx.x;              // b*2048 + s
    int s = bs & (SS - 1);
    const float* xrow = x + (size_t)bs * DMODEL;
#pragma unroll
    for (int dd = 0; dd < 4; ++dd) {
        int d = threadIdx.x + dd * 256;
        float w0 = cw[d * 4 + 0], w1 = cw[d * 4 + 1], w2 = cw[d * 4 + 2], w3 = cw[d * 4 + 3];
        float acc = cb[d] + w3 * xrow[d];
        if (s >= 1) acc += w2 * xrow[d - DMODEL];
        if (s >= 2) acc += w1 * xrow[d - 2 * DMODEL];
        if (s >= 3) acc += w0 * xrow[d - 3 * DMODEL];
        float sig = 1.f / (1.f + __expf(-acc));
        xc[(size_t)bs * DMODEL + d] = acc * sig;
    }
}

// ---------------- headwise projections (bf16 MFMA GEMM) ----------------
// grid: (M/64=128, 512/64=8, 8 instances). instance z = h*2 + pair.
// pair0: {i,f} from x_conv ; pair1: {z,o} from x.
// gates layout: [b][h][s][g][d]  (coalesced epilogue writes)
__global__ void k_gemm(const float* __restrict__ x, const float* __restrict__ xc,
                       const float* __restrict__ wi, const float* __restrict__ wf,
                       const float* __restrict__ wz, const float* __restrict__ wo,
                       float* __restrict__ gates) {
    int h = blockIdx.z >> 1, pair = blockIdx.z & 1;
    const float* A = pair ? x : xc;
    int n0 = blockIdx.y * 64;  // in [0,512)
    const float* W = (n0 < 256) ? (pair ? wz : wi) : (pair ? wo : wf);
    int nl = n0 & 255;
    int m0 = blockIdx.x * 64;

    __shared__ __align__(16) __hip_bfloat16 Al[64][72];
    __shared__ __align__(16) __hip_bfloat16 Bl[64][72];

    int tid = threadIdx.x;
    int lane = tid & 63, wv = tid >> 6;
    f32x4 acc[4] = {};

    for (int k0 = 0; k0 < 256; k0 += 64) {
        __syncthreads();
#pragma unroll
        for (int i = 0; i < 4; ++i) {
            int f4 = tid + i * 256;
            int r = f4 >> 4, c4 = (f4 & 15) * 4;
            const float* srcA = A + (size_t)(m0 + r) * DMODEL + h * DH + k0 + c4;
            float4 v = *(const float4*)srcA;
            Al[r][c4 + 0] = __float2bfloat16(v.x);
            Al[r][c4 + 1] = __float2bfloat16(v.y);
            Al[r][c4 + 2] = __float2bfloat16(v.z);
            Al[r][c4 + 3] = __float2bfloat16(v.w);
            const float* srcB = W + (size_t)(h * DH + nl + r) * DH + k0 + c4;
            float4 u = *(const float4*)srcB;
            Bl[r][c4 + 0] = __float2bfloat16(u.x);
            Bl[r][c4 + 1] = __float2bfloat16(u.y);
            Bl[r][c4 + 2] = __float2bfloat16(u.z);
            Bl[r][c4 + 3] = __float2bfloat16(u.w);
        }
        __syncthreads();
#pragma unroll
        for (int kk = 0; kk < 64; kk += 32) {
            bf16x8 a = *(const bf16x8*)&Al[wv * 16 + (lane & 15)][kk + (lane >> 4) * 8];
#pragma unroll
            for (int nt = 0; nt < 4; ++nt) {
                bf16x8 bfr = *(const bf16x8*)&Bl[nt * 16 + (lane & 15)][kk + (lane >> 4) * 8];
                acc[nt] = __builtin_amdgcn_mfma_f32_16x16x32_bf16(a, bfr, acc[nt], 0, 0, 0);
            }
        }
    }
    // epilogue: gates[b][h][s][g][d]
#pragma unroll
    for (int nt = 0; nt < 4; ++nt)
#pragma unroll
        for (int r = 0; r < 4; ++r) {
            int m = m0 + wv * 16 + (lane >> 4) * 4 + r;
            int n = n0 + nt * 16 + (lane & 15);
            int b = m >> 11, s = m & (SS - 1);
            int g = pair * 2 + (n >> 8), d = n & 255;
            gates[((((size_t)(b * NH + h)) * SS + s) * 4 + g) * DH + d] = acc[nt][r];
        }
}

// ---------------- weight prep: per-column int8 quantization of R ----------------
// Wq[(h*64 + j)*1024 + col]: 4 i8 packed (byte i = R[h][4j+i][col] quantized)
__global__ void k_prep(const float* __restrict__ R, int* __restrict__ Wq,
                       float* __restrict__ scales) {
    int colid = blockIdx.x * 4 + (threadIdx.x >> 6);  // 0..4095
    int lane = threadIdx.x & 63;
    int h = colid >> 10, k = colid & 1023;
    const float* base = R + (size_t)h * 256 * 1024 + k;
    float v[4];
    float mx = 0.f;
#pragma unroll
    for (int i = 0; i < 4; ++i) {
        v[i] = base[(size_t)(lane * 4 + i) * 1024];
        mx = fmaxf(mx, fabsf(v[i]));
    }
    for (int off = 32; off; off >>= 1) mx = fmaxf(mx, __shfl_xor(mx, off));
    mx = fmaxf(mx, 1e-30f);
    float scale = mx * (1.f / 127.f);
    float inv = 127.f / mx;
    int pk = 0;
#pragma unroll
    for (int i = 0; i < 4; ++i) {
        int q = (int)rintf(v[i] * inv);
        q = max(-127, min(127, q));
        pk |= (q & 255) << (8 * i);
    }
    Wq[(h * 64 + lane) * 1024 + k] = pk;
    if (lane == 0) scales[h * 1024 + k] = scale;
}

// ---------------- the sequential sLSTM scan (hybrid VALU + MFMA) ----------------
// 16 blocks, one per (b,h). 256 threads = 4 waves (1 wave/SIMD, full 512-reg
// budget). Thread d owns cell state d plus the dot4 columns f[d], z[d], o[d]
// (192 dwords int8, in-register) -> rf/rz/ro computed locally on the VALU pipe
// (192 v_dot4 = 384 cyc/SIMD). Gate i's 256 columns run CONCURRENTLY on the
// matrix pipe (16 x mfma_i32_16x16x64_i8 per SIMD ~= 326 cyc): wave wv owns
// tiles wv*4..wv*4+3, A = broadcast hq (all 16 rows equal -> row 0 = exact dot),
// B-fragments register/AGPR-resident (MFMA reads them natively). ri is moved
// from MFMA lanes 0..15 to cell threads by 4 __shfl + static selects -- no
// rec[] LDS round-trip, ONE barrier/step, hq double-buffered. h operand reads
// are wave-uniform ds_read_b128 (broadcast, conflict-free). VALU and MFMA
// pipes overlap (m114): step ~= max(dots, MFMA) + cell, vs their SUM before.
__launch_bounds__(256, 1)
__global__ void k_scan(const float* __restrict__ gates, const int* __restrict__ Wq,
                       const float* __restrict__ scales, const float* __restrict__ bias,
                       float* __restrict__ y) {
    int bh = blockIdx.x;
    int h = bh & 3;
    int d = threadIdx.x;        // 0..255, also the cell index
    int lane = d & 63;
    int wv = d >> 6;            // wave 0..3
    int kg = lane >> 4;         // K-group 0..3 within MFMA fragment
    int cl = lane & 15;         // col-within-tile (= d & 15)

    __shared__ __align__(16) signed char hq[2][256];

    // ---- dot4 weights: own columns f[d], z[d], o[d] (192 arch dwords)
    int wf[64], wz[64], wo[64];
#pragma unroll
    for (int j = 0; j < 64; ++j) {
        const int* row = Wq + (size_t)(h * 64 + j) * 1024 + d;
        wf[j] = row[256];
        wz[j] = row[512];
        wo[j] = row[768];
    }

    // ---- MFMA B-fragments for gate i: wave wv owns cols wv*64 .. wv*64+63
    // (tiles tt=0..3). Layout identical to round-4's hardware-verified one.
    i32x4 bfr[4][4];
#pragma unroll
    for (int tt = 0; tt < 4; ++tt) {
        int col = wv * 64 + tt * 16 + cl;
#pragma unroll
        for (int c = 0; c < 4; ++c)
#pragma unroll
            for (int j4 = 0; j4 < 4; ++j4)
                bfr[tt][c][j4] = Wq[(h * 64 + c * 16 + kg * 4 + j4) * 1024 + col];
    }
    i32x4 acc[4];
#pragma unroll
    for (int tt = 0; tt < 4; ++tt) acc[tt] = (i32x4){0, 0, 0, 0};

    float cmi = scales[h * 1024 + d] * (1.f / 127.f);
    float cmf = scales[h * 1024 + 256 + d] * (1.f / 127.f);
    float cmz = scales[h * 1024 + 512 + d] * (1.f / 127.f);
    float cmo = scales[h * 1024 + 768 + d] * (1.f / 127.f);
    float bi = bias[(0 * NH + h) * DH + d];
    float bf_ = bias[(1 * NH + h) * DH + d];
    float bz = bias[(2 * NH + h) * DH + d];
    float bo = bias[(3 * NH + h) * DH + d];

    float c_ = 0.f, n_ = 0.f, mstate = 0.f;
    const float* gbase = gates + (size_t)bh * SS * 1024;
    float* ybase = y + (size_t)bh * SS * DH;

    if (d < 32) ((i32x4*)hq)[d] = (i32x4){0, 0, 0, 0};  // zero both buffers
    __syncthreads();

    // gate ping-pong (distance-2 prefetch; rides under dots/MFMA + barrier)
    float gA0 = gbase[d], gA1 = gbase[256 + d], gA2 = gbase[512 + d], gA3 = gbase[768 + d];
    float gB0 = gbase[1024 + d], gB1 = gbase[1024 + 256 + d];
    float gB2 = gbase[1024 + 512 + d], gB3 = gbase[1024 + 768 + d];

#define DOT3(JJ, HV)                  \
    af = dot4i8(af, wf[JJ], (HV));    \
    az = dot4i8(az, wz[JJ], (HV));    \
    ao = dot4i8(ao, wo[JJ], (HV));

#define SCAN_STEP(P, G0, G1, G2, G3, SCUR)                                     \
    {                                                                          \
        int sp = (SCUR) + 2 < SS ? (SCUR) + 2 : SS - 1;                        \
        const float* gp = gbase + (size_t)sp * 1024 + d;                       \
        float p0 = gp[0], p1 = gp[256], p2 = gp[512], p3 = gp[768];            \
        const i32x4* hp = (const i32x4*)hq[P];                                 \
        /* MFMA phase: gate i on the matrix pipe */                            \
        i32x4 a0 = hp[kg], a1 = hp[4 + kg], a2 = hp[8 + kg], a3 = hp[12 + kg]; \
        acc[0].x = 0; acc[1].x = 0; acc[2].x = 0; acc[3].x = 0;                \
        _Pragma("unroll") for (int tt = 0; tt < 4; ++tt)                       \
            acc[tt] = __builtin_amdgcn_mfma_i32_16x16x64_i8(a0, bfr[tt][0], acc[tt], 0, 0, 0); \
        _Pragma("unroll") for (int tt = 0; tt < 4; ++tt)                       \
            acc[tt] = __builtin_amdgcn_mfma_i32_16x16x64_i8(a1, bfr[tt][1], acc[tt], 0, 0, 0); \
        _Pragma("unroll") for (int tt = 0; tt < 4; ++tt)                       \
            acc[tt] = __builtin_amdgcn_mfma_i32_16x16x64_i8(a2, bfr[tt][2], acc[tt], 0, 0, 0); \
        _Pragma("unroll") for (int tt = 0; tt < 4; ++tt)                       \
            acc[tt] = __builtin_amdgcn_mfma_i32_16x16x64_i8(a3, bfr[tt][3], acc[tt], 0, 0, 0); \
        /* dot4 phase: gates f,z,o on the VALU pipe (overlaps MFMA) */         \
        int af = 0, az = 0, ao = 0;                                            \
        _Pragma("unroll") for (int cc = 0; cc < 4; ++cc) {                     \
            i32x4 h0 = hp[cc * 4 + 0], h1 = hp[cc * 4 + 1];                    \
            i32x4 h2 = hp[cc * 4 + 2], h3 = hp[cc * 4 + 3];                    \
            DOT3(cc * 16 + 0, h0.x)  DOT3(cc * 16 + 1, h0.y)                   \
            DOT3(cc * 16 + 2, h0.z)  DOT3(cc * 16 + 3, h0.w)                   \
            DOT3(cc * 16 + 4, h1.x)  DOT3(cc * 16 + 5, h1.y)                   \
            DOT3(cc * 16 + 6, h1.z)  DOT3(cc * 16 + 7, h1.w)                   \
            DOT3(cc * 16 + 8, h2.x)  DOT3(cc * 16 + 9, h2.y)                   \
            DOT3(cc * 16 + 10, h2.z) DOT3(cc * 16 + 11, h2.w)                  \
            DOT3(cc * 16 + 12, h3.x) DOT3(cc * 16 + 13, h3.y)                  \
            DOT3(cc * 16 + 14, h3.z) DOT3(cc * 16 + 15, h3.w)                  \
        }                                                                      \
        /* ri: pull row-0 MFMA result from lane (d&15), tile (d>>4)&3 */       \
        int s0 = __shfl(acc[0].x, cl);                                         \
        int s1 = __shfl(acc[1].x, cl);                                         \
        int s2 = __shfl(acc[2].x, cl);                                         \
        int s3 = __shfl(acc[3].x, cl);                                         \
        int v01 = (d & 16) ? s1 : s0;                                          \
        int v23 = (d & 16) ? s3 : s2;                                          \
        int ri_raw = (d & 32) ? v23 : v01;                                     \
        float rawi = (G0) + (float)ri_raw * cmi + bi;                          \
        float rawf = (G1) + (float)af * cmf + bf_;                             \
        float rawz = (G2) + (float)az * cmz + bz;                              \
        float rawo = (G3) + (float)ao * cmo + bo;                              \
        float lsf = fminf(rawf, 0.f) - __logf(1.f + __expf(-fabsf(rawf)));     \
        float lfm = mstate + lsf;                                              \
        float mn = fmaxf(rawi, lfm);                                           \
        float ig = __expf(rawi - mn);                                          \
        float fg = __expf(lfm - mn);                                           \
        float az_ = fabsf(rawz);                                               \
        float e2 = __expf(-2.f * az_);                                         \
        float th = (1.f - e2) / (1.f + e2);                                    \
        th = rawz < 0.f ? -th : th;                                            \
        c_ = fg * c_ + ig * th;                                                \
        n_ = fg * n_ + ig;                                                     \
        mstate = mn;                                                           \
        float so = 1.f / (1.f + __expf(-rawo));                                \
        float hv = so * c_ / n_;                                               \
        ybase[(size_t)(SCUR)*DH + d] = hv;                                     \
        hq[(P) ^ 1][d] = (signed char)(int)rintf(hv * 127.f);                  \
        G0 = p0; G1 = p1; G2 = p2; G3 = p3;                                    \
        wg_barrier();                                                          \
    }

    for (int s = 0; s < SS; s += 2) {
        SCAN_STEP(0, gA0, gA1, gA2, gA3, s)
        SCAN_STEP(1, gB0, gB1, gB2, gB3, s + 1)
    }
#undef SCAN_STEP
#undef DOT3
}

// ---------------- multihead layernorm + transpose ----------------
__global__ void k_ln(const float* __restrict__ y, const float* __restrict__ gsc,
                     const float* __restrict__ gbi, float* __restrict__ out) {
    int bid = blockIdx.x;  // bh*2048 + s
    int s = bid & (SS - 1);
    int bh = bid >> 11;
    int b = bh >> 2, h = bh & 3;
    int d = threadIdx.x;
    float v = y[(size_t)bid * DH + d];
    float s1 = v, s2 = v * v;
    for (int off = 32; off; off >>= 1) {
        s1 += __shfl_xor(s1, off);
        s2 += __shfl_xor(s2, off);
    }
    __shared__ float a1[4], a2[4];
    int wv = threadIdx.x >> 6, ln = threadIdx.x & 63;
    if (ln == 0) { a1[wv] = s1; a2[wv] = s2; }
    __syncthreads();
    s1 = a1[0] + a1[1] + a1[2] + a1[3];
    s2 = a2[0] + a2[1] + a2[2] + a2[3];
    float mu = s1 * (1.f / 256.f);
    float var = s2 * (1.f / 256.f) - mu * mu;
    float rs = rsqrtf(var + 1e-6f);
    float o = (v - mu) * rs * gsc[h * DH + d] + gbi[h * DH + d];
    out[((size_t)(b * SS + s)) * DMODEL + h * DH + d] = o;
}

extern "C" void kernel_launch(void* const* d_in, const int* in_sizes, int n_in,
                              void* d_out, int out_size, void* d_ws, size_t ws_size,
                              hipStream_t stream) {
    (void)in_sizes; (void)n_in; (void)out_size; (void)ws_size;
    const float* x = (const float*)d_in[0];
    const float* cw = (const float*)d_in[1];
    const float* cb = (const float*)d_in[2];
    const float* wi = (const float*)d_in[3];
    const float* wf = (const float*)d_in[4];
    const float* wz = (const float*)d_in[5];
    const float* wo = (const float*)d_in[6];
    const float* R = (const float*)d_in[7];
    const float* cbias = (const float*)d_in[8];
    const float* gsc = (const float*)d_in[9];
    const float* gbi = (const float*)d_in[10];
    float* out = (float*)d_out;

    char* ws = (char*)d_ws;
    float* xc = (float*)ws;                           // 33,554,432 B
    float* gates = (float*)(ws + 33554432ull);        // 134,217,728 B
    float* yb = (float*)(ws + 167772160ull);          // 33,554,432 B
    int* Wq = (int*)(ws + 201326592ull);              // 1,048,576 B
    float* scales = (float*)(ws + 202375168ull);      // 16,384 B

    k_prep<<<1024, 256, 0, stream>>>(R, Wq, scales);
    k_conv<<<BB * SS, 256, 0, stream>>>(x, cw, cb, xc);
    k_gemm<<<dim3(128, 8, 8), 256, 0, stream>>>(x, xc, wi, wf, wz, wo, gates);
    k_scan<<<16, 256, 0, stream>>>(gates, Wq, scales, cbias, yb);
    k_ln<<<BB * SS * NH, 256, 0, stream>>>(yb, gsc, gbi, out);
}